// Round 11
// baseline (170.056 us; speedup 1.0000x reference)
//
#include <hip/hip_runtime.h>

typedef __bf16 bf16_t;
typedef bf16_t bf16x8 __attribute__((ext_vector_type(8)));
typedef bf16_t bf16x4 __attribute__((ext_vector_type(4)));
typedef float f32x4 __attribute__((ext_vector_type(4)));

__device__ __forceinline__ f32x4 mfma16(bf16x8 a, bf16x8 b, f32x4 c) {
  return __builtin_amdgcn_mfma_f32_16x16x32_bf16(a, b, c, 0, 0, 0);
}

__device__ __forceinline__ void gload16(const void* g, void* l) {
  __builtin_amdgcn_global_load_lds(
      (const __attribute__((address_space(1))) void*)g,
      (__attribute__((address_space(3))) void*)l, 16, 0, 0);
}

// ------- prep: weight transposes only: [K][N] f32 -> [N][768] bf16 -------
__global__ void prepw_kernel(const float* __restrict__ wq, const float* __restrict__ wp,
                             bf16_t* __restrict__ wqt, bf16_t* __restrict__ wpt) {
  __shared__ bf16_t tile[32][33];
  const int t = blockIdx.x;
  const int ty = t / 96, txb = t % 96;
  const float* in;
  bf16_t* out;
  int N, n0;
  if (txb < 72) { in = wq; out = wqt; N = 2304; n0 = txb * 32; }
  else          { in = wp; out = wpt; N = 768;  n0 = (txb - 72) * 32; }
  const int k0 = ty * 32;
  const int tx = threadIdx.x & 31, tyy = threadIdx.x >> 5;
#pragma unroll
  for (int ph = 0; ph < 4; ++ph) {
    int k = tyy + ph * 8;
    tile[k][tx] = (bf16_t)in[(size_t)(k0 + k) * N + n0 + tx];
  }
  __syncthreads();
#pragma unroll
  for (int ph = 0; ph < 4; ++ph) {
    int n = tyy + ph * 8;
    out[(size_t)(n0 + n) * 768 + k0 + tx] = tile[tx][n];
  }
}

// ------- GEMM1: qkv = cvt(X_f32) * Wt^T, A staged as f32 via global_load_lds -------
// BK=32, BN=128, 4 waves (2x2). LDS: A f32 dbuf 32KiB + B bf16 dbuf 16KiB = 48KiB
// -> 3 blocks/CU. A fragments converted f32->bf16 at read time (VALU was idle).
// Round-6 proven sync: stage(next) -> compute(cur) -> __syncthreads().
__global__ __launch_bounds__(256, 3) void gemm1_xf32(
    const float* __restrict__ X, const bf16_t* __restrict__ Bt,
    bf16_t* __restrict__ Cout) {
  constexpr int K = 768, NKT = 24, NBN = 18, JPB = 3;
  __shared__ float Af[2][128 * 32];
  __shared__ bf16_t Bs[2][128 * 32];
  const int tid = threadIdx.x, lane = tid & 63, w = tid >> 6;
  const int wm = w >> 1, wn = w & 1;
  const int lr = lane & 15, kg = lane >> 4;

  // XCD-chunked remap; 3 jobs/block share one bm (A panel constant)
  const int G = gridDim.x, bid = blockIdx.x;
  const int lb = (bid & 7) * (G >> 3) + (bid >> 3);
  const int start = lb * JPB;
  const int bm = start / NBN;
  const int bn0 = start - bm * NBN;
  const float* Xj = X + (size_t)bm * (128 * K);

  // A: 128 rows x 32 f32 = 128B/row = 8 x 16B slots; swizzle p^(r&7)
  auto stageA = [&](int buf, int k0) {
#pragma unroll
    for (int it = 0; it < 4; ++it) {
      int c = it * 256 + tid;
      int r = c >> 3, p = c & 7;
      gload16(Xj + (size_t)r * K + k0 + ((p ^ (r & 7)) << 2), &Af[buf][c * 4]);
    }
  };
  // B: 128 rows x 32 bf16 = 64B/row = 4 x 16B slots; swizzle p^((r>>1)&3) (r6-proven)
  auto stageB = [&](int buf, const bf16_t* Bj, int k0) {
#pragma unroll
    for (int it = 0; it < 2; ++it) {
      int c = it * 256 + tid;
      int r = c >> 2, p = c & 3;
      gload16(Bj + (size_t)r * K + k0 + ((p ^ ((r >> 1) & 3)) << 3), &Bs[buf][c * 8]);
    }
  };

  const int phB = kg ^ ((lr >> 1) & 3);   // B phys slot
  const int sA0 = (2 * kg) ^ (lr & 7);    // A phys slots (f32x4 units)
  const int sA1 = sA0 ^ 1;

  const bf16_t* Bj = Bt + (size_t)bn0 * (128 * K);
  stageA(0, 0);
  stageB(0, Bj, 0);
  __syncthreads();
  int buf = 0;

  for (int j = 0; j < JPB; ++j) {
    const int bn = bn0 + j;
    const bf16_t* BjN = Bt + (size_t)(bn + 1) * (128 * K);
    f32x4 acc[4][4];
#pragma unroll
    for (int i = 0; i < 4; ++i)
#pragma unroll
      for (int n = 0; n < 4; ++n) acc[i][n] = (f32x4){0.f, 0.f, 0.f, 0.f};

    for (int kt = 0; kt < NKT; ++kt) {
      const bool injob = (kt + 1 < NKT);
      if (injob) {
        stageA(buf ^ 1, (kt + 1) << 5);
        stageB(buf ^ 1, Bj, (kt + 1) << 5);
      } else if (j + 1 < JPB) {
        stageA(buf ^ 1, 0);
        stageB(buf ^ 1, BjN, 0);
      }

      bf16x8 af[4], bfv[4];
#pragma unroll
      for (int mq = 0; mq < 4; ++mq) {
        int rr = wm * 64 + mq * 16 + lr;
        f32x4 a0 = *(const f32x4*)&Af[buf][rr * 32 + sA0 * 4];
        f32x4 a1 = *(const f32x4*)&Af[buf][rr * 32 + sA1 * 4];
        bf16x8 o;
        o[0] = (bf16_t)a0[0]; o[1] = (bf16_t)a0[1]; o[2] = (bf16_t)a0[2]; o[3] = (bf16_t)a0[3];
        o[4] = (bf16_t)a1[0]; o[5] = (bf16_t)a1[1]; o[6] = (bf16_t)a1[2]; o[7] = (bf16_t)a1[3];
        af[mq] = o;
      }
#pragma unroll
      for (int nq = 0; nq < 4; ++nq) {
        int rr = wn * 64 + nq * 16 + lr;
        bfv[nq] = *(const bf16x8*)&Bs[buf][(rr << 5) + (phB << 3)];
      }
#pragma unroll
      for (int mq = 0; mq < 4; ++mq)
#pragma unroll
        for (int nq = 0; nq < 4; ++nq)
          acc[mq][nq] = mfma16(af[mq], bfv[nq], acc[mq][nq]);

      __syncthreads();
      buf ^= 1;
    }

    const int row0 = bm * 128 + wm * 64 + kg * 4;
    const int col0 = bn * 128 + wn * 64 + lr;
#pragma unroll
    for (int mq = 0; mq < 4; ++mq)
#pragma unroll
      for (int nq = 0; nq < 4; ++nq)
#pragma unroll
        for (int rr = 0; rr < 4; ++rr)
          Cout[(size_t)(row0 + mq * 16 + rr) * 2304 + (col0 + nq * 16)] =
              (bf16_t)acc[mq][nq][rr];

    Bj = BjN;
  }
}

// ------- GEMM2: 128x128, BK=32, grid 768 = exactly 1 round at 3 blocks/CU -------
__global__ __launch_bounds__(256, 3) void gemm2_kernel(
    const bf16_t* __restrict__ A, const bf16_t* __restrict__ Bt,
    float* __restrict__ Cout) {
  constexpr int K = 768, NKT = 24, NBN = 6;
  __shared__ bf16_t As[2][128 * 32];
  __shared__ bf16_t Bs[2][128 * 32];
  const int tid = threadIdx.x, lane = tid & 63, w = tid >> 6;
  const int wm = w >> 1, wn = w & 1;
  const int lr = lane & 15, kg = lane >> 4;

  const int G = gridDim.x, bid = blockIdx.x;
  const int lb = (bid & 7) * (G >> 3) + (bid >> 3);
  const int bm = lb / NBN, bn = lb - bm * NBN;
  const bf16_t* Aj = A + (size_t)bm * (128 * K);
  const bf16_t* Bj = Bt + (size_t)bn * (128 * K);

  auto stage = [&](int buf, int k0) {
#pragma unroll
    for (int it = 0; it < 2; ++it) {
      int c = it * 256 + tid;
      int r = c >> 2, p = c & 3;
      int so = k0 + ((p ^ ((r >> 1) & 3)) << 3);
      gload16(Aj + (size_t)r * K + so, &As[buf][c * 8]);
      gload16(Bj + (size_t)r * K + so, &Bs[buf][c * 8]);
    }
  };

  stage(0, 0);
  __syncthreads();
  int buf = 0;

  f32x4 acc[4][4];
#pragma unroll
  for (int i = 0; i < 4; ++i)
#pragma unroll
    for (int n = 0; n < 4; ++n) acc[i][n] = (f32x4){0.f, 0.f, 0.f, 0.f};

  const int ph = kg ^ ((lr >> 1) & 3);

  for (int kt = 0; kt < NKT; ++kt) {
    if (kt + 1 < NKT) stage(buf ^ 1, (kt + 1) << 5);
    bf16x8 af[4], bfv[4];
#pragma unroll
    for (int mq = 0; mq < 4; ++mq) {
      int rr = wm * 64 + mq * 16 + lr;
      af[mq] = *(const bf16x8*)&As[buf][(rr << 5) + (ph << 3)];
    }
#pragma unroll
    for (int nq = 0; nq < 4; ++nq) {
      int rr = wn * 64 + nq * 16 + lr;
      bfv[nq] = *(const bf16x8*)&Bs[buf][(rr << 5) + (ph << 3)];
    }
#pragma unroll
    for (int mq = 0; mq < 4; ++mq)
#pragma unroll
      for (int nq = 0; nq < 4; ++nq)
        acc[mq][nq] = mfma16(af[mq], bfv[nq], acc[mq][nq]);
    __syncthreads();
    buf ^= 1;
  }

  const int row0 = bm * 128 + wm * 64 + kg * 4;
  const int col0 = bn * 128 + wn * 64 + lr;
#pragma unroll
  for (int mq = 0; mq < 4; ++mq)
#pragma unroll
    for (int nq = 0; nq < 4; ++nq)
#pragma unroll
      for (int rr = 0; rr < 4; ++rr)
        Cout[(size_t)(row0 + mq * 16 + rr) * 768 + (col0 + nq * 16)] = acc[mq][nq][rr];
}

// ---------------- causal attention: one block per (b,h) ----------------
#define ATT_H 12
__global__ __launch_bounds__(256, 2) void attn_kernel(const bf16_t* __restrict__ qkv,
                                                      bf16_t* __restrict__ obuf) {
  __shared__ bf16_t Ks[128 * 72];
  __shared__ bf16_t Vt[64 * 136];
  __shared__ bf16_t Ps[128 * 136];
  const int tid = threadIdx.x, lane = tid & 63, w = tid >> 6;
  const int lr = lane & 15, kg = lane >> 4;
  const int bh = blockIdx.x;
  const int b = bh / ATT_H, h = bh % ATT_H;
  const size_t base = (size_t)b * 128 * 2304;
  const int hoff = h * 64;

#pragma unroll
  for (int it = 0; it < 4; ++it) {
    int idx = it * 256 + tid;
    int r = idx >> 3, slot = idx & 7;
    bf16x8 v = *(const bf16x8*)&qkv[base + (size_t)r * 2304 + 768 + hoff + slot * 8];
    *(bf16x8*)&Ks[r * 72 + slot * 8] = v;
  }
#pragma unroll 4
  for (int it = 0; it < 32; ++it) {
    int idx = it * 256 + tid;
    int t = idx >> 6, d = idx & 63;
    Vt[d * 136 + t] = qkv[base + (size_t)t * 2304 + 1536 + hoff + d];
  }
  const int qrow0 = w * 32;
  bf16x8 qf[2][2];
#pragma unroll
  for (int mt = 0; mt < 2; ++mt)
#pragma unroll
    for (int kk = 0; kk < 2; ++kk)
      qf[mt][kk] = *(const bf16x8*)&qkv[base + (size_t)(qrow0 + mt * 16 + lr) * 2304 + hoff +
                                        kk * 32 + kg * 8];
  __syncthreads();

  const int NT = 2 * w + 2;
  f32x4 acc[2][8];
#pragma unroll
  for (int mt = 0; mt < 2; ++mt)
#pragma unroll
    for (int nt = 0; nt < 8; ++nt) acc[mt][nt] = (f32x4){0.f, 0.f, 0.f, 0.f};

#pragma unroll
  for (int nt = 0; nt < 8; ++nt) {
    if (nt < NT) {
#pragma unroll
      for (int kk = 0; kk < 2; ++kk) {
        bf16x8 kf = *(const bf16x8*)&Ks[(nt * 16 + lr) * 72 + kk * 32 + kg * 8];
        acc[0][nt] = mfma16(qf[0][kk], kf, acc[0][nt]);
        acc[1][nt] = mfma16(qf[1][kk], kf, acc[1][nt]);
      }
    }
  }

#pragma unroll
  for (int mt = 0; mt < 2; ++mt) {
#pragma unroll
    for (int rr = 0; rr < 4; ++rr) {
      const int row = qrow0 + mt * 16 + kg * 4 + rr;
      float m = -1e30f;
#pragma unroll
      for (int nt = 0; nt < 8; ++nt) {
        if (nt < NT) {
          int col = nt * 16 + lr;
          float sv = acc[mt][nt][rr] * 0.125f;
          sv = (col <= row) ? sv : -1e30f;
          acc[mt][nt][rr] = sv;
          m = fmaxf(m, sv);
        }
      }
      m = fmaxf(m, __shfl_xor(m, 1));
      m = fmaxf(m, __shfl_xor(m, 2));
      m = fmaxf(m, __shfl_xor(m, 4));
      m = fmaxf(m, __shfl_xor(m, 8));
      float ssum = 0.f;
#pragma unroll
      for (int nt = 0; nt < 8; ++nt) {
        if (nt < NT) {
          float p = __builtin_amdgcn_exp2f((acc[mt][nt][rr] - m) * 1.44269504f);
          acc[mt][nt][rr] = p;
          ssum += p;
        }
      }
      ssum += __shfl_xor(ssum, 1);
      ssum += __shfl_xor(ssum, 2);
      ssum += __shfl_xor(ssum, 4);
      ssum += __shfl_xor(ssum, 8);
      float inv = 1.0f / ssum;
#pragma unroll
      for (int nt = 0; nt < 8; ++nt) {
        if (nt < NT) Ps[row * 136 + nt * 16 + lr] = (bf16_t)(acc[mt][nt][rr] * inv);
      }
    }
  }

  f32x4 oacc[2][4];
#pragma unroll
  for (int mt = 0; mt < 2; ++mt)
#pragma unroll
    for (int dt = 0; dt < 4; ++dt) oacc[mt][dt] = (f32x4){0.f, 0.f, 0.f, 0.f};

  const int KS = w + 1;
#pragma unroll
  for (int ks = 0; ks < 4; ++ks) {
    if (ks < KS) {
      bf16x8 pa0 = *(const bf16x8*)&Ps[(qrow0 + lr) * 136 + ks * 32 + kg * 8];
      bf16x8 pa1 = *(const bf16x8*)&Ps[(qrow0 + 16 + lr) * 136 + ks * 32 + kg * 8];
#pragma unroll
      for (int dt = 0; dt < 4; ++dt) {
        bf16x8 vb = *(const bf16x8*)&Vt[(dt * 16 + lr) * 136 + ks * 32 + kg * 8];
        oacc[0][dt] = mfma16(pa0, vb, oacc[0][dt]);
        oacc[1][dt] = mfma16(pa1, vb, oacc[1][dt]);
      }
    }
  }

#pragma unroll
  for (int mt = 0; mt < 2; ++mt)
#pragma unroll
    for (int dt = 0; dt < 4; ++dt)
#pragma unroll
      for (int rr = 0; rr < 4; ++rr) {
        int t = qrow0 + mt * 16 + kg * 4 + rr;
        obuf[((size_t)b * 128 + t) * 768 + hoff + dt * 16 + lr] = (bf16_t)oacc[mt][dt][rr];
      }
}

// ---------------- launch ----------------
extern "C" void kernel_launch(void* const* d_in, const int* in_sizes, int n_in,
                              void* d_out, int out_size, void* d_ws, size_t ws_size,
                              hipStream_t stream) {
  const float* x = (const float*)d_in[0];       // [128,128,768]
  const float* w_qkv = (const float*)d_in[1];   // [768,2304]
  const float* w_proj = (const float*)d_in[2];  // [768,768]
  float* out = (float*)d_out;
  char* ws = (char*)d_ws;

  bf16_t* wqkvt  = (bf16_t*)(ws);              // 2304*768*2    =  3,538,944
  bf16_t* wprojt = (bf16_t*)(ws + 3538944);    // 768*768*2     =  1,179,648
  bf16_t* qkv    = (bf16_t*)(ws + 4718592);    // 16384*2304*2  = 75,497,472
  bf16_t* obuf   = (bf16_t*)(ws + 80216064);   // 16384*768*2   = 25,165,824

  prepw_kernel<<<dim3(2304), dim3(256), 0, stream>>>(w_qkv, w_proj, wqkvt, wprojt);
  // GEMM1: x read as f32 directly (no convert pass); 768 blocks x 3 jobs
  gemm1_xf32<<<dim3(768), dim3(256), 0, stream>>>(x, wqkvt, qkv);
  attn_kernel<<<dim3(1536), dim3(256), 0, stream>>>(qkv, obuf);
  // GEMM2: 768 jobs = 768 blocks, 1 each; 3 blocks/CU = exactly 1 round
  gemm2_kernel<<<dim3(768), dim3(256), 0, stream>>>(obuf, wprojt, out);
}